// Round 6
// baseline (408.769 us; speedup 1.0000x reference)
//
#include <hip/hip_runtime.h>
#include <hip/hip_cooperative_groups.h>

namespace cg = cooperative_groups;

typedef unsigned short u16;
typedef unsigned int u32;
typedef __bf16 bf16x8 __attribute__((ext_vector_type(8)));
typedef float floatx4 __attribute__((ext_vector_type(4)));
typedef unsigned short u16x8 __attribute__((ext_vector_type(8)));
typedef unsigned int u32x4 __attribute__((ext_vector_type(4)));

static constexpr int B_ = 4;
static constexpr int N_ = 16384;
static constexpr int M_ = 512;

__device__ __forceinline__ u16 f2bf(float f) {
    u32 u = __float_as_uint(f);
    u32 r = (u + 0x7fffu + ((u >> 16) & 1u)) >> 16;
    return (u16)r;
}
__device__ __forceinline__ float bf2f(u16 x) {
    return __uint_as_float(((u32)x) << 16);
}
__device__ __forceinline__ u32 pack2(float a, float b) {
    return (u32)f2bf(a) | ((u32)f2bf(b) << 16);
}

struct WConvArgs { const float* src[12]; };

static constexpr int RS = 136;
static constexpr int RS2 = 520;
static constexpr int RS3 = 648;

// ---------------------------------------------------------------------------
// In-LDS in-place conv. PF = weight prefetch ring size (power of 2).
// ---------------------------------------------------------------------------
template <int KS, int CF, int RF, int PF, int RSx>
__device__ __forceinline__ void conv_inplace(u16* act, const u16* __restrict__ W0, int KP,
                                             const float* __restrict__ bias, int cb,
                                             int l15, int quad) {
    floatx4 acc[RF][CF];
#pragma unroll
    for (int rf = 0; rf < RF; ++rf)
#pragma unroll
        for (int cf = 0; cf < CF; ++cf) acc[rf][cf] = (floatx4){0.f, 0.f, 0.f, 0.f};

    bf16x8 bw[PF][CF];
#pragma unroll
    for (int p = 0; p < PF - 1; ++p)
        if (p < KS)
#pragma unroll
            for (int cf = 0; cf < CF; ++cf)
                bw[p][cf] = *(const bf16x8*)(W0 + (size_t)(cb + cf * 16 + l15) * KP +
                                             p * 32 + quad * 8);

#pragma unroll
    for (int ks = 0; ks < KS; ++ks) {
        if (ks + PF - 1 < KS) {
#pragma unroll
            for (int cf = 0; cf < CF; ++cf)
                bw[(ks + PF - 1) & (PF - 1)][cf] =
                    *(const bf16x8*)(W0 + (size_t)(cb + cf * 16 + l15) * KP +
                                     (ks + PF - 1) * 32 + quad * 8);
        }
#pragma unroll
        for (int rf = 0; rf < RF; ++rf) {
            bf16x8 a = *(const bf16x8*)(act + (rf * 16 + l15) * RSx + ks * 32 + quad * 8);
#pragma unroll
            for (int cf = 0; cf < CF; ++cf)
                acc[rf][cf] = __builtin_amdgcn_mfma_f32_16x16x32_bf16(a, bw[ks & (PF - 1)][cf], acc[rf][cf], 0, 0, 0);
        }
    }
    __syncthreads();   // all waves' reads complete before in-place writes
#pragma unroll
    for (int cf = 0; cf < CF; ++cf) {
        float bs = bias[cb + cf * 16 + l15];
#pragma unroll
        for (int rf = 0; rf < RF; ++rf)
#pragma unroll
            for (int r = 0; r < 4; ++r)
                act[(rf * 16 + quad * 4 + r) * RSx + cb + cf * 16 + l15] =
                    f2bf(fmaxf(acc[rf][cf][r] + bs, 0.0f));
    }
    __syncthreads();
}

// ===========================================================================
// MEGA cooperative kernel: 256 blocks x 512 threads, 1 block/CU. Block blk
// owns nodes 8*blk..8*blk+7 through all phases; sidx/knn stay in LDS.
// Phase 1: weight cvt (grid-stride) + knn (wave/node) + ball query (wave/node)
// grid.sync  (Wbf visible)
// Phase 2: stage1 conv1-5, wave-per-node on its own 64-row LDS strip -> h
// grid.sync  (h visible)
// Phase 3: stage23 (proven 85.6us body), knn from LDS, out.
// ===========================================================================
__global__ __launch_bounds__(512, 2) void mega_kernel(
    const float* __restrict__ x, const float* __restrict__ sn,
    const float* __restrict__ node, WConvArgs wa,
    u16* __restrict__ Wbf, u16* __restrict__ h,
    const float* __restrict__ b1, const float* __restrict__ b2,
    const float* __restrict__ b3, const float* __restrict__ b4,
    const float* __restrict__ b5,
    const float* __restrict__ bb1, const float* __restrict__ bb2,
    const float* __restrict__ bb3, const float* __restrict__ ba1,
    const float* __restrict__ ba2,
    const float* __restrict__ bm1, const float* __restrict__ bm2,
    const float* __restrict__ w3, const float* __restrict__ b3f,
    float* __restrict__ out) {
    __shared__ __align__(16) u16 actU[512 * RS];   // 139,264 B (phase2; phase3 reuses front)
    __shared__ __align__(16) u16 mvL[8][64];
    __shared__ int sidx[8][64];
    __shared__ int scnt[8];
    __shared__ int knnL[8][9];

    int blk = blockIdx.x;              // 0..255
    int node0 = blk * 8;
    int tid = threadIdx.x, wave = tid >> 6, lane = tid & 63;
    int quad = lane >> 4, l15 = lane & 15;
    int g = node0 + wave;              // this wave's node
    int b = g >> 9, m = g & 511;

    // ---------------- Phase 1 ----------------
    {   // weight conversion, grid-stride (all blocks cover 1,198,080 elems)
        const int CI[12] = {6, 64, 64, 128, 128, 131, 256, 256, 512, 512, 640, 512};
        const int KP[12] = {32, 64, 64, 128, 128, 160, 256, 256, 512, 512, 640, 512};
        const int OFF[13] = {0, 2048, 6144, 10240, 26624, 43008, 83968, 149504,
                             215040, 477184, 739328, 1067008, 1198080};
#pragma unroll 1
        for (int e = blk * 512 + tid; e < 1198080; e += 131072) {
            int w = 0;
            while (e >= OFF[w + 1]) ++w;
            int local = e - OFF[w];
            int kp = KP[w];
            int co = local / kp, k = local - co * kp;
            float v = 0.0f;
            if (w == 5) {   // knnb1 K-layout: 0..2 coords, 8..135 feat1
                if (k < 3) v = wa.src[5][(size_t)co * 131 + k];
                else if (k >= 8 && k < 136) v = wa.src[5][(size_t)co * 131 + (k - 5)];
            } else if (k < CI[w]) {
                v = wa.src[w][(size_t)co * CI[w] + k];
            }
            Wbf[e] = f2bf(v);
        }
    }

    float nx = node[((size_t)b * 3 + 0) * M_ + m];
    float ny = node[((size_t)b * 3 + 1) * M_ + m];
    float nz = node[((size_t)b * 3 + 2) * M_ + m];
    float aa = nx * nx + ny * ny + nz * nz;

    {   // knn for node g (one wave)
        const float* nb = node + (size_t)b * 3 * M_;
        float dist[8];
        int didx[8];
#pragma unroll
        for (int i = 0; i < 8; ++i) {
            int n = lane + i * 64;
            float px = nb[n], py = nb[M_ + n], pz = nb[2 * M_ + n];
            float bb = px * px + py * py + pz * pz;
            float ab = nx * px + ny * py + nz * pz;
            dist[i] = aa + bb - 2.0f * ab;
            didx[i] = n;
        }
#pragma unroll 1
        for (int r = 0; r < 9; ++r) {
            float bv = dist[0]; int bi = didx[0]; int bslot = 0;
#pragma unroll
            for (int i = 1; i < 8; ++i) {
                if (dist[i] < bv || (dist[i] == bv && didx[i] < bi)) {
                    bv = dist[i]; bi = didx[i]; bslot = i;
                }
            }
            float rv = bv; int ri = bi;
            for (int off = 32; off > 0; off >>= 1) {
                float ov = __shfl_down(rv, off);
                int   oi = __shfl_down(ri, off);
                if (ov < rv || (ov == rv && oi < ri)) { rv = ov; ri = oi; }
            }
            ri = __shfl(ri, 0);
            if (lane == 0) knnL[wave][r] = ri;
            if (bi == ri) dist[bslot] = 3.0e38f;
        }
    }

    {   // ball query for node g: full scan, early break (proven round-3 logic)
        const float* xb = x + (size_t)b * 3 * N_;
        int cnt = 0;
#pragma unroll 1
        for (int n0 = 0; n0 < N_; n0 += 256) {
            float px[4], py[4], pz[4];
#pragma unroll
            for (int i = 0; i < 4; ++i) {
                int n = n0 + i * 64 + lane;
                px[i] = xb[n]; py[i] = xb[N_ + n]; pz[i] = xb[2 * N_ + n];
            }
#pragma unroll
            for (int i = 0; i < 4; ++i) {
                float bb = px[i] * px[i] + py[i] * py[i] + pz[i] * pz[i];
                float d = aa + bb - 2.0f * (nx * px[i] + ny * py[i] + nz * pz[i]);
                bool inb = d < 4.0f;
                unsigned long long mask = __ballot(inb);
                if (inb && cnt < 64) {
                    int pos = cnt + __popcll(mask & ((1ull << lane) - 1ull));
                    if (pos < 64) sidx[wave][pos] = n0 + i * 64 + lane;
                }
                cnt += __popcll(mask);
            }
            if (cnt >= 64) break;   // wave-uniform
        }
        if (lane == 0) scnt[wave] = cnt < 64 ? cnt : 64;
    }
    __syncthreads();
    __threadfence();
    cg::this_grid().sync();

    // ---------------- Phase 2: stage1, wave-per-node ----------------
    u16* base = actU + wave * 64 * RS;
    {   // gather: lane -> row lane of this wave's node
        int c = scnt[wave];
        int j = (c == 0) ? 0 : sidx[wave][lane < c ? lane : 0];
        const float* xb = x + (size_t)b * 3 * N_;
        const float* sb = sn + (size_t)b * 3 * N_;
        float c0 = xb[j] - nx;
        float c1 = xb[N_ + j] - ny;
        float c2 = xb[2 * N_ + j] - nz;
        float s0 = sb[j], s1 = sb[N_ + j], s2 = sb[2 * N_ + j];
        u16* r = base + lane * RS;
        *(u32*)(r)     = pack2(c0, c1);
        *(u32*)(r + 2) = pack2(c2, s0);
        *(u32*)(r + 4) = pack2(s1, s2);
        *(u32*)(r + 6) = 0u;
        u32x4* z = (u32x4*)(r + 8);
        z[0] = (u32x4){0u, 0u, 0u, 0u};
        z[1] = (u32x4){0u, 0u, 0u, 0u};
        z[2] = (u32x4){0u, 0u, 0u, 0u};
    }
    __syncthreads();

    {   // conv1: K=32 (6 used), co 64 (CF=4), RF=4
        bf16x8 bw[4];
#pragma unroll
        for (int cf = 0; cf < 4; ++cf)
            bw[cf] = *(const bf16x8*)(Wbf + (size_t)(cf * 16 + l15) * 32 + quad * 8);
        floatx4 c[4][4];
#pragma unroll
        for (int rf = 0; rf < 4; ++rf) {
            bf16x8 a = *(const bf16x8*)(base + (rf * 16 + l15) * RS + quad * 8);
#pragma unroll
            for (int cf = 0; cf < 4; ++cf)
                c[rf][cf] = __builtin_amdgcn_mfma_f32_16x16x32_bf16(a, bw[cf], (floatx4){0.f,0.f,0.f,0.f}, 0, 0, 0);
        }
#pragma unroll
        for (int cf = 0; cf < 4; ++cf) {
            float bias = b1[cf * 16 + l15];
#pragma unroll
            for (int rf = 0; rf < 4; ++rf)
#pragma unroll
                for (int r = 0; r < 4; ++r)
                    base[(rf * 16 + quad * 4 + r) * RS + cf * 16 + l15] = f2bf(fmaxf(c[rf][cf][r] + bias, 0.0f));
        }
        __syncthreads();
    }

    {   // conv2 / conv3: K=64, co 64 (CF=4), RF=4; conv3 also node rowmax->mvL
        const int WOFF23[2] = {2048, 6144};
        const float* bp23[2] = {b2, b3};
#pragma unroll 1
        for (int cv = 0; cv < 2; ++cv) {
            const u16* Wp = Wbf + WOFF23[cv];
            bf16x8 bw[2][4];
#pragma unroll
            for (int ks = 0; ks < 2; ++ks)
#pragma unroll
                for (int cf = 0; cf < 4; ++cf)
                    bw[ks][cf] = *(const bf16x8*)(Wp + (size_t)(cf * 16 + l15) * 64 + ks * 32 + quad * 8);
            floatx4 c[4][4] = {};
#pragma unroll
            for (int ks = 0; ks < 2; ++ks)
#pragma unroll
                for (int rf = 0; rf < 4; ++rf) {
                    bf16x8 a = *(const bf16x8*)(base + (rf * 16 + l15) * RS + ks * 32 + quad * 8);
#pragma unroll
                    for (int cf = 0; cf < 4; ++cf)
                        c[rf][cf] = __builtin_amdgcn_mfma_f32_16x16x32_bf16(a, bw[ks][cf], c[rf][cf], 0, 0, 0);
                }
#pragma unroll
            for (int cf = 0; cf < 4; ++cf) {
                float bias = bp23[cv][cf * 16 + l15];
                float mxv = 0.0f;
#pragma unroll
                for (int rf = 0; rf < 4; ++rf)
#pragma unroll
                    for (int r = 0; r < 4; ++r) {
                        float v = fmaxf(c[rf][cf][r] + bias, 0.0f);
                        mxv = fmaxf(mxv, v);
                        base[(rf * 16 + quad * 4 + r) * RS + cf * 16 + l15] = f2bf(v);
                    }
                if (cv == 1) {
                    mxv = fmaxf(mxv, __shfl_xor(mxv, 16));
                    mxv = fmaxf(mxv, __shfl_xor(mxv, 32));
                    if (quad == 0) mvL[wave][cf * 16 + l15] = f2bf(mxv);
                }
            }
            __syncthreads();
        }
    }

    {   // conv4: K=128 ([conv3 | rowmax]), co 128 in two passes (cp=1 first:
        // writes cols 64..127 which are not conv4 inputs; cp=0 last).
#pragma unroll 1
        for (int cp = 1; cp >= 0; --cp) {
            const u16* Wp = Wbf + 10240 + (size_t)(cp * 64) * 128;
            bf16x8 bw[4][4];
#pragma unroll
            for (int cf = 0; cf < 4; ++cf)
#pragma unroll
                for (int ks = 0; ks < 4; ++ks)
                    bw[cf][ks] = *(const bf16x8*)(Wp + (size_t)(cf * 16 + l15) * 128 + ks * 32 + quad * 8);
            floatx4 c[4][4] = {};
#pragma unroll
            for (int ks = 0; ks < 4; ++ks) {
                bf16x8 amv;
                if (ks >= 2) amv = *(const bf16x8*)(&mvL[wave][(ks - 2) * 32 + quad * 8]);
#pragma unroll
                for (int rf = 0; rf < 4; ++rf) {
                    bf16x8 a = (ks < 2) ? *(const bf16x8*)(base + (rf * 16 + l15) * RS + ks * 32 + quad * 8)
                                        : amv;
#pragma unroll
                    for (int cf = 0; cf < 4; ++cf)
                        c[rf][cf] = __builtin_amdgcn_mfma_f32_16x16x32_bf16(a, bw[cf][ks], c[rf][cf], 0, 0, 0);
                }
            }
#pragma unroll
            for (int cf = 0; cf < 4; ++cf) {
                float bias = b4[cp * 64 + cf * 16 + l15];
#pragma unroll
                for (int rf = 0; rf < 4; ++rf)
#pragma unroll
                    for (int r = 0; r < 4; ++r)
                        base[(rf * 16 + quad * 4 + r) * RS + cp * 64 + cf * 16 + l15] =
                            f2bf(fmaxf(c[rf][cf][r] + bias, 0.0f));
            }
        }
        __syncthreads();
    }

    {   // conv5 + per-node maxpool -> h[g][0:128], two co passes
#pragma unroll 1
        for (int cp = 0; cp < 2; ++cp) {
            const u16* Wp = Wbf + 26624 + (size_t)(cp * 64) * 128;
            bf16x8 bw[4][4];
#pragma unroll
            for (int cf = 0; cf < 4; ++cf)
#pragma unroll
                for (int ks = 0; ks < 4; ++ks)
                    bw[cf][ks] = *(const bf16x8*)(Wp + (size_t)(cf * 16 + l15) * 128 + ks * 32 + quad * 8);
            floatx4 c[4][4] = {};
#pragma unroll
            for (int ks = 0; ks < 4; ++ks)
#pragma unroll
                for (int rf = 0; rf < 4; ++rf) {
                    bf16x8 a = *(const bf16x8*)(base + (rf * 16 + l15) * RS + ks * 32 + quad * 8);
#pragma unroll
                    for (int cf = 0; cf < 4; ++cf)
                        c[rf][cf] = __builtin_amdgcn_mfma_f32_16x16x32_bf16(a, bw[cf][ks], c[rf][cf], 0, 0, 0);
                }
#pragma unroll
            for (int cf = 0; cf < 4; ++cf) {
                float bias = b5[cp * 64 + cf * 16 + l15];
                float mxv = 0.0f;
#pragma unroll
                for (int rf = 0; rf < 4; ++rf)
#pragma unroll
                    for (int r = 0; r < 4; ++r)
                        mxv = fmaxf(mxv, fmaxf(c[rf][cf][r] + bias, 0.0f));
                mxv = fmaxf(mxv, __shfl_xor(mxv, 16));
                mxv = fmaxf(mxv, __shfl_xor(mxv, 32));
                if (quad == 0)
                    h[(size_t)g * 128 + cp * 64 + cf * 16 + l15] = f2bf(mxv);
            }
        }
    }
    __syncthreads();
    __threadfence();
    cg::this_grid().sync();

    // ---------------- Phase 3: stage23 (proven body) ----------------
    u16* act = actU;
    u16* mlpT = actU + 80 * RS2;

    for (int e = tid; e < 80 * 20; e += 512)
        *(u16x8*)(act + (e / 20) * RS2 + (e % 20) * 8) = (u16x8){0,0,0,0,0,0,0,0};
    __syncthreads();
    for (int e = tid; e < 72 * 3; e += 512) {
        int r = e / 3, c = e - r * 3;
        int li = r / 9;
        int j = knnL[li][r % 9];
        int nodei = node0 + li;
        float v = node[((size_t)b * 3 + c) * M_ + j] - node[((size_t)b * 3 + c) * M_ + (nodei & 511)];
        act[r * RS2 + c] = f2bf(v);
    }
    for (int e = tid; e < 72 * 16; e += 512) {
        int r = e >> 4, s = e & 15;
        int j = knnL[r / 9][r % 9];
        *(u16x8*)(act + r * RS2 + 8 + s * 8) =
            *(const u16x8*)(h + (size_t)(b * 512 + j) * 128 + s * 8);
    }
    __syncthreads();

    conv_inplace<5, 2, 5, 4, RS2>(act, Wbf + 43008, 160, bb1, wave * 32, l15, quad);
    conv_inplace<8, 2, 5, 4, RS2>(act, Wbf + 83968, 256, bb2, wave * 32, l15, quad);
    conv_inplace<8, 2, 5, 4, RS2>(act, Wbf + 149504, 256, bb3, wave * 32, l15, quad);

    for (int e = tid; e < 8 * 32; e += 512) {
        int li = e >> 5, s = e & 31;
        int r0 = li * 9;
        float mx[8];
#pragma unroll
        for (int i = 0; i < 8; ++i) mx[i] = -3.0e38f;
#pragma unroll
        for (int kk = 0; kk < 9; ++kk) {
            u16x8 v = *(const u16x8*)(act + (r0 + kk) * RS2 + s * 8);
#pragma unroll
            for (int i = 0; i < 8; ++i) mx[i] = fmaxf(mx[i], bf2f(v[i]));
        }
        u16x8 o;
#pragma unroll
        for (int i = 0; i < 8; ++i) o[i] = f2bf(mx[i]);
#pragma unroll
        for (int kk = 0; kk < 9; ++kk)
            *(u16x8*)(act + (r0 + kk) * RS2 + 256 + s * 8) = o;
    }
    __syncthreads();

    conv_inplace<16, 4, 5, 4, RS2>(act, Wbf + 215040, 512, ba1, wave * 64, l15, quad);
    conv_inplace<16, 4, 5, 4, RS2>(act, Wbf + 477184, 512, ba2, wave * 64, l15, quad);

    // feat2 pool -> mlpT[*, 128:640]
    for (int e = tid; e < 8 * 64; e += 512) {
        int li = e >> 6, s = e & 63;
        int r0 = li * 9;
        float mx[8];
#pragma unroll
        for (int i = 0; i < 8; ++i) mx[i] = -3.0e38f;
#pragma unroll
        for (int kk = 0; kk < 9; ++kk) {
            u16x8 v = *(const u16x8*)(act + (r0 + kk) * RS2 + s * 8);
#pragma unroll
            for (int i = 0; i < 8; ++i) mx[i] = fmaxf(mx[i], bf2f(v[i]));
        }
        u16x8 o;
#pragma unroll
        for (int i = 0; i < 8; ++i) o[i] = f2bf(mx[i]);
        *(u16x8*)(mlpT + li * RS3 + 128 + s * 8) = o;
    }
    for (int e = tid; e < 8 * 16; e += 512) {
        int li = e >> 4, s = e & 15;
        *(u16x8*)(mlpT + li * RS3 + s * 8) =
            *(const u16x8*)(h + (size_t)(node0 + li) * 128 + s * 8);
    }
    for (int e = tid; e < 8 * 80; e += 512) {
        int r = e / 80, seg = e - r * 80;
        *(u16x8*)(mlpT + (8 + r) * RS3 + seg * 8) = (u16x8){0,0,0,0,0,0,0,0};
    }
    __syncthreads();

    conv_inplace<20, 4, 1, 4, RS3>(mlpT, Wbf + 739328, 640, bm1, wave * 64, l15, quad);
    conv_inplace<16, 2, 1, 4, RS3>(mlpT, Wbf + 1067008, 512, bm2, wave * 32, l15, quad);

    if (tid < 32) {
        int li = tid >> 2, oc = tid & 3;
        const u16* row = mlpT + li * RS3;
        const float* wrow = w3 + oc * 256;
        float a = 0.0f;
        for (int c = 0; c < 256; c += 4) {
            a += bf2f(row[c]) * wrow[c];
            a += bf2f(row[c + 1]) * wrow[c + 1];
            a += bf2f(row[c + 2]) * wrow[c + 2];
            a += bf2f(row[c + 3]) * wrow[c + 3];
        }
        a += b3f[oc];
        int nodei = node0 + li;
        int bo = nodei >> 9, mo = nodei & 511;
        if (oc < 3) {
            float nv = node[((size_t)bo * 3 + oc) * M_ + mo];
            out[((size_t)bo * 3 + oc) * M_ + mo] = nv;
            out[6144 + ((size_t)bo * 3 + oc) * M_ + mo] = nv + a;
        } else {
            out[12288 + nodei] = fmaxf(a, 0.0f) + log1pf(expf(-fabsf(a))) + 0.001f;
        }
    }
}

// ===========================================================================
// Fallback path: round-5 three-kernel pipeline (used only if cooperative
// launch is rejected by the runtime / capture).
// ===========================================================================
__global__ __launch_bounds__(256) void prep_kernel(
    const float* __restrict__ node, int* __restrict__ knn,
    WConvArgs wa, u16* __restrict__ Wbf) {
    int bid = blockIdx.x;
    int tid = threadIdx.x, wave = tid >> 6, lane = tid & 63;

    if (bid < 512) {
        int bm = bid * 4 + wave;
        int b = bm >> 9, m = bm & 511;
        const float* nb = node + (size_t)b * 3 * M_;
        float nx = nb[m], ny = nb[M_ + m], nz = nb[2 * M_ + m];
        float aa = nx * nx + ny * ny + nz * nz;
        float dist[8];
        int didx[8];
#pragma unroll
        for (int i = 0; i < 8; ++i) {
            int n = lane + i * 64;
            float px = nb[n], py = nb[M_ + n], pz = nb[2 * M_ + n];
            float bb = px * px + py * py + pz * pz;
            float ab = nx * px + ny * py + nz * pz;
            dist[i] = aa + bb - 2.0f * ab;
            didx[i] = n;
        }
        for (int r = 0; r < 9; ++r) {
            float bv = dist[0]; int bi = didx[0]; int bslot = 0;
#pragma unroll
            for (int i = 1; i < 8; ++i) {
                if (dist[i] < bv || (dist[i] == bv && didx[i] < bi)) {
                    bv = dist[i]; bi = didx[i]; bslot = i;
                }
            }
            float rv = bv; int ri = bi;
            for (int off = 32; off > 0; off >>= 1) {
                float ov = __shfl_down(rv, off);
                int   oi = __shfl_down(ri, off);
                if (ov < rv || (ov == rv && oi < ri)) { rv = ov; ri = oi; }
            }
            ri = __shfl(ri, 0);
            if (lane == 0) knn[(size_t)bm * 9 + r] = ri;
            if (bi == ri) dist[bslot] = 3.0e38f;
        }
    } else {
        const int CI[12] = {6, 64, 64, 128, 128, 131, 256, 256, 512, 512, 640, 512};
        const int KP[12] = {32, 64, 64, 128, 128, 160, 256, 256, 512, 512, 640, 512};
        const int OFF[13] = {0, 2048, 6144, 10240, 26624, 43008, 83968, 149504,
                             215040, 477184, 739328, 1067008, 1198080};
        int e = (bid - 512) * 256 + tid;
        int w = 0;
        while (e >= OFF[w + 1]) ++w;
        int local = e - OFF[w];
        int kp = KP[w];
        int co = local / kp, k = local - co * kp;
        float v = 0.0f;
        if (w == 5) {
            if (k < 3) v = wa.src[5][(size_t)co * 131 + k];
            else if (k >= 8 && k < 136) v = wa.src[5][(size_t)co * 131 + (k - 5)];
        } else if (k < CI[w]) {
            v = wa.src[w][(size_t)co * CI[w] + k];
        }
        Wbf[e] = f2bf(v);
    }
}

__device__ __forceinline__ bf16x8 ldsA(const u16* act, int rf, int l15, int quad, int ks) {
    return *(const bf16x8*)(act + (rf * 16 + l15) * RS + ks * 32 + quad * 8);
}
__device__ __forceinline__ bf16x8 ldW(const u16* W, int ks, int l15, int quad, int kstride) {
    return *(const bf16x8*)(W + (size_t)l15 * kstride + ks * 32 + quad * 8);
}

__global__ __launch_bounds__(256, 4) void fused_stage1_kernel(
    const float* __restrict__ x, const float* __restrict__ sn,
    const float* __restrict__ node,
    const u16* __restrict__ Wbf,
    const float* __restrict__ b1, const float* __restrict__ b2,
    const float* __restrict__ b3, const float* __restrict__ b4,
    const float* __restrict__ b5, u16* __restrict__ h) {
    __shared__ __align__(16) u16 act[64 * RS];
    __shared__ __align__(16) u16 mv[64];
    __shared__ int sidx[4][64];
    __shared__ int scnt[4];
    int bm = blockIdx.x;
    int b = bm >> 9, m = bm & 511;
    int tid = threadIdx.x, wave = tid >> 6, lane = tid & 63;
    int quad = lane >> 4, l15 = lane & 15;

    {
        const float* xb = x + (size_t)b * 3 * N_;
        float nx = node[((size_t)b * 3 + 0) * M_ + m];
        float ny = node[((size_t)b * 3 + 1) * M_ + m];
        float nz = node[((size_t)b * 3 + 2) * M_ + m];
        float aa = nx * nx + ny * ny + nz * nz;
        int cnt = 0;
        int base = wave * 4096;
#pragma unroll 1
        for (int n0 = base; n0 < base + 4096; n0 += 256) {
            float px[4], py[4], pz[4];
#pragma unroll
            for (int i = 0; i < 4; ++i) {
                int n = n0 + i * 64 + lane;
                px[i] = xb[n]; py[i] = xb[N_ + n]; pz[i] = xb[2 * N_ + n];
            }
#pragma unroll
            for (int i = 0; i < 4; ++i) {
                float bb = px[i] * px[i] + py[i] * py[i] + pz[i] * pz[i];
                float d = aa + bb - 2.0f * (nx * px[i] + ny * py[i] + nz * pz[i]);
                bool inb = d < 4.0f;
                unsigned long long mask = __ballot(inb);
                if (inb && cnt < 64) {
                    int pos = cnt + __popcll(mask & ((1ull << lane) - 1ull));
                    if (pos < 64) sidx[wave][pos] = n0 + i * 64 + lane;
                }
                cnt += __popcll(mask);
            }
            if (cnt >= 64) break;
        }
        if (lane == 0) scnt[wave] = cnt;
    }
    __syncthreads();

    if (tid < 64) {
        int total = scnt[0] + scnt[1] + scnt[2] + scnt[3];
        int j = 0;
        if (total > 0) {
            int lim = total < 64 ? total : 64;
            int slot = tid < lim ? tid : 0;
            int w = 0, pre = 0;
            while (w < 3 && slot >= pre + scnt[w]) { pre += scnt[w]; ++w; }
            j = sidx[w][slot - pre];
        }
        const float* xb = x + (size_t)b * 3 * N_;
        const float* sb = sn + (size_t)b * 3 * N_;
        float c0 = xb[j]          - node[((size_t)b * 3 + 0) * M_ + m];
        float c1 = xb[N_ + j]     - node[((size_t)b * 3 + 1) * M_ + m];
        float c2 = xb[2 * N_ + j] - node[((size_t)b * 3 + 2) * M_ + m];
        float s0 = sb[j], s1 = sb[N_ + j], s2 = sb[2 * N_ + j];
        u16* r = act + tid * RS;
        *(u32*)(r)     = pack2(c0, c1);
        *(u32*)(r + 2) = pack2(c2, s0);
        *(u32*)(r + 4) = pack2(s1, s2);
        *(u32*)(r + 6) = 0u;
        u32x4* z = (u32x4*)(r + 8);
        z[0] = (u32x4){0u, 0u, 0u, 0u};
        z[1] = (u32x4){0u, 0u, 0u, 0u};
        z[2] = (u32x4){0u, 0u, 0u, 0u};
    }
    __syncthreads();

    {
        const u16* Wp = Wbf + (size_t)(wave * 16) * 32;
        bf16x8 bw = ldW(Wp, 0, l15, quad, 32);
        floatx4 c[4];
#pragma unroll
        for (int rf = 0; rf < 4; ++rf) {
            bf16x8 a = ldsA(act, rf, l15, quad, 0);
            c[rf] = __builtin_amdgcn_mfma_f32_16x16x32_bf16(a, bw, (floatx4){0.f,0.f,0.f,0.f}, 0, 0, 0);
        }
        float bias = b1[wave * 16 + l15];
        __syncthreads();
#pragma unroll
        for (int rf = 0; rf < 4; ++rf)
#pragma unroll
            for (int r = 0; r < 4; ++r)
                act[(rf * 16 + quad * 4 + r) * RS + wave * 16 + l15] = f2bf(fmaxf(c[rf][r] + bias, 0.0f));
        __syncthreads();
    }

    const int WOFF23[2] = {2048, 6144};
    const float* bp23[2] = {b2, b3};
#pragma unroll 1
    for (int cv = 0; cv < 2; ++cv) {
        const u16* Wp = Wbf + WOFF23[cv] + (size_t)(wave * 16) * 64;
        bf16x8 bw0 = ldW(Wp, 0, l15, quad, 64);
        bf16x8 bw1 = ldW(Wp, 1, l15, quad, 64);
        floatx4 c[4] = {};
#pragma unroll
        for (int ks = 0; ks < 2; ++ks)
#pragma unroll
            for (int rf = 0; rf < 4; ++rf) {
                bf16x8 a = ldsA(act, rf, l15, quad, ks);
                c[rf] = __builtin_amdgcn_mfma_f32_16x16x32_bf16(a, ks ? bw1 : bw0, c[rf], 0, 0, 0);
            }
        float bias = bp23[cv][wave * 16 + l15];
        float mx = 0.0f;
#pragma unroll
        for (int rf = 0; rf < 4; ++rf)
#pragma unroll
            for (int r = 0; r < 4; ++r)
                mx = fmaxf(mx, fmaxf(c[rf][r] + bias, 0.0f));
        __syncthreads();
#pragma unroll
        for (int rf = 0; rf < 4; ++rf)
#pragma unroll
            for (int r = 0; r < 4; ++r)
                act[(rf * 16 + quad * 4 + r) * RS + wave * 16 + l15] = f2bf(fmaxf(c[rf][r] + bias, 0.0f));
        if (cv == 1) {
            mx = fmaxf(mx, __shfl_xor(mx, 16));
            mx = fmaxf(mx, __shfl_xor(mx, 32));
            if (quad == 0) mv[wave * 16 + l15] = f2bf(mx);
        }
        __syncthreads();
    }

    {
        const u16* Wp = Wbf + 10240 + (size_t)(wave * 32) * 128;
        bf16x8 bw[2][4];
#pragma unroll
        for (int cf = 0; cf < 2; ++cf)
#pragma unroll
            for (int ks = 0; ks < 4; ++ks)
                bw[cf][ks] = ldW(Wp + (size_t)cf * 16 * 128, ks, l15, quad, 128);
        floatx4 c[4][2] = {};
#pragma unroll
        for (int ks = 0; ks < 4; ++ks) {
            bf16x8 amv;
            if (ks >= 2) amv = *(const bf16x8*)(&mv[(ks - 2) * 32 + quad * 8]);
#pragma unroll
            for (int rf = 0; rf < 4; ++rf) {
                bf16x8 a = (ks < 2) ? ldsA(act, rf, l15, quad, ks) : amv;
#pragma unroll
                for (int cf = 0; cf < 2; ++cf)
                    c[rf][cf] = __builtin_amdgcn_mfma_f32_16x16x32_bf16(a, bw[cf][ks], c[rf][cf], 0, 0, 0);
            }
        }
        float bias[2];
#pragma unroll
        for (int cf = 0; cf < 2; ++cf) bias[cf] = b4[wave * 32 + cf * 16 + l15];
        __syncthreads();
#pragma unroll
        for (int rf = 0; rf < 4; ++rf)
#pragma unroll
            for (int cf = 0; cf < 2; ++cf)
#pragma unroll
                for (int r = 0; r < 4; ++r)
                    act[(rf * 16 + quad * 4 + r) * RS + wave * 32 + cf * 16 + l15] =
                        f2bf(fmaxf(c[rf][cf][r] + bias[cf], 0.0f));
        __syncthreads();
    }

    {
        const u16* Wp = Wbf + 26624 + (size_t)(wave * 32) * 128;
        bf16x8 bw[2][4];
#pragma unroll
        for (int cf = 0; cf < 2; ++cf)
#pragma unroll
            for (int ks = 0; ks < 4; ++ks)
                bw[cf][ks] = ldW(Wp + (size_t)cf * 16 * 128, ks, l15, quad, 128);
        floatx4 c[4][2] = {};
#pragma unroll
        for (int ks = 0; ks < 4; ++ks)
#pragma unroll
            for (int rf = 0; rf < 4; ++rf) {
                bf16x8 a = ldsA(act, rf, l15, quad, ks);
#pragma unroll
                for (int cf = 0; cf < 2; ++cf)
                    c[rf][cf] = __builtin_amdgcn_mfma_f32_16x16x32_bf16(a, bw[cf][ks], c[rf][cf], 0, 0, 0);
            }
#pragma unroll
        for (int cf = 0; cf < 2; ++cf) {
            float bias = b5[wave * 32 + cf * 16 + l15];
            float mx = 0.0f;
#pragma unroll
            for (int rf = 0; rf < 4; ++rf)
#pragma unroll
                for (int r = 0; r < 4; ++r)
                    mx = fmaxf(mx, fmaxf(c[rf][cf][r] + bias, 0.0f));
            mx = fmaxf(mx, __shfl_xor(mx, 16));
            mx = fmaxf(mx, __shfl_xor(mx, 32));
            if (quad == 0)
                h[(size_t)bm * 128 + wave * 32 + cf * 16 + l15] = f2bf(mx);
        }
    }
}

__global__ __launch_bounds__(512, 2) void fused_stage23_kernel(
    const float* __restrict__ node, const u16* __restrict__ h,
    const int* __restrict__ knn, const u16* __restrict__ Wbf,
    const float* __restrict__ bb1, const float* __restrict__ bb2,
    const float* __restrict__ bb3, const float* __restrict__ ba1,
    const float* __restrict__ ba2,
    const float* __restrict__ bm1, const float* __restrict__ bm2,
    const float* __restrict__ w3, const float* __restrict__ b3,
    float* __restrict__ out) {
    __shared__ __align__(16) u16 act[80 * RS2 + 16 * RS3];
    u16* mlpT = act + 80 * RS2;
    int blk = blockIdx.x;
    int node0 = blk * 8;
    int b = node0 >> 9;
    int tid = threadIdx.x, wave = tid >> 6, lane = tid & 63;
    int quad = lane >> 4, l15 = lane & 15;
    (void)lane;

    for (int e = tid; e < 80 * 20; e += 512)
        *(u16x8*)(act + (e / 20) * RS2 + (e % 20) * 8) = (u16x8){0,0,0,0,0,0,0,0};
    __syncthreads();
    for (int e = tid; e < 72 * 3; e += 512) {
        int r = e / 3, c = e - r * 3;
        int nodei = node0 + r / 9;
        int j = knn[(size_t)nodei * 9 + (r % 9)];
        float v = node[((size_t)b * 3 + c) * M_ + j] - node[((size_t)b * 3 + c) * M_ + (nodei & 511)];
        act[r * RS2 + c] = f2bf(v);
    }
    for (int e = tid; e < 72 * 16; e += 512) {
        int r = e >> 4, s = e & 15;
        int nodei = node0 + r / 9;
        int j = knn[(size_t)nodei * 9 + (r % 9)];
        *(u16x8*)(act + r * RS2 + 8 + s * 8) =
            *(const u16x8*)(h + (size_t)(b * 512 + j) * 128 + s * 8);
    }
    __syncthreads();

    conv_inplace<5, 2, 5, 4, RS2>(act, Wbf + 43008, 160, bb1, wave * 32, l15, quad);
    conv_inplace<8, 2, 5, 4, RS2>(act, Wbf + 83968, 256, bb2, wave * 32, l15, quad);
    conv_inplace<8, 2, 5, 4, RS2>(act, Wbf + 149504, 256, bb3, wave * 32, l15, quad);

    for (int e = tid; e < 8 * 32; e += 512) {
        int li = e >> 5, s = e & 31;
        int r0 = li * 9;
        float mx[8];
#pragma unroll
        for (int i = 0; i < 8; ++i) mx[i] = -3.0e38f;
#pragma unroll
        for (int kk = 0; kk < 9; ++kk) {
            u16x8 v = *(const u16x8*)(act + (r0 + kk) * RS2 + s * 8);
#pragma unroll
            for (int i = 0; i < 8; ++i) mx[i] = fmaxf(mx[i], bf2f(v[i]));
        }
        u16x8 o;
#pragma unroll
        for (int i = 0; i < 8; ++i) o[i] = f2bf(mx[i]);
#pragma unroll
        for (int kk = 0; kk < 9; ++kk)
            *(u16x8*)(act + (r0 + kk) * RS2 + 256 + s * 8) = o;
    }
    __syncthreads();

    conv_inplace<16, 4, 5, 4, RS2>(act, Wbf + 215040, 512, ba1, wave * 64, l15, quad);
    conv_inplace<16, 4, 5, 4, RS2>(act, Wbf + 477184, 512, ba2, wave * 64, l15, quad);

    for (int e = tid; e < 8 * 64; e += 512) {
        int li = e >> 6, s = e & 63;
        int r0 = li * 9;
        float mx[8];
#pragma unroll
        for (int i = 0; i < 8; ++i) mx[i] = -3.0e38f;
#pragma unroll
        for (int kk = 0; kk < 9; ++kk) {
            u16x8 v = *(const u16x8*)(act + (r0 + kk) * RS2 + s * 8);
#pragma unroll
            for (int i = 0; i < 8; ++i) mx[i] = fmaxf(mx[i], bf2f(v[i]));
        }
        u16x8 o;
#pragma unroll
        for (int i = 0; i < 8; ++i) o[i] = f2bf(mx[i]);
        *(u16x8*)(mlpT + li * RS3 + 128 + s * 8) = o;
    }
    for (int e = tid; e < 8 * 16; e += 512) {
        int li = e >> 4, s = e & 15;
        *(u16x8*)(mlpT + li * RS3 + s * 8) =
            *(const u16x8*)(h + (size_t)(node0 + li) * 128 + s * 8);
    }
    for (int e = tid; e < 8 * 80; e += 512) {
        int r = e / 80, seg = e - r * 80;
        *(u16x8*)(mlpT + (8 + r) * RS3 + seg * 8) = (u16x8){0,0,0,0,0,0,0,0};
    }
    __syncthreads();

    conv_inplace<20, 4, 1, 4, RS3>(mlpT, Wbf + 739328, 640, bm1, wave * 64, l15, quad);
    conv_inplace<16, 2, 1, 4, RS3>(mlpT, Wbf + 1067008, 512, bm2, wave * 32, l15, quad);

    if (tid < 32) {
        int li = tid >> 2, oc = tid & 3;
        const u16* row = mlpT + li * RS3;
        const float* wrow = w3 + oc * 256;
        float a = 0.0f;
        for (int c = 0; c < 256; c += 4) {
            a += bf2f(row[c]) * wrow[c];
            a += bf2f(row[c + 1]) * wrow[c + 1];
            a += bf2f(row[c + 2]) * wrow[c + 2];
            a += bf2f(row[c + 3]) * wrow[c + 3];
        }
        a += b3[oc];
        int nodei = node0 + li;
        int bo = nodei >> 9, m = nodei & 511;
        if (oc < 3) {
            float nv = node[((size_t)bo * 3 + oc) * M_ + m];
            out[((size_t)bo * 3 + oc) * M_ + m] = nv;
            out[6144 + ((size_t)bo * 3 + oc) * M_ + m] = nv + a;
        } else {
            out[12288 + nodei] = fmaxf(a, 0.0f) + log1pf(expf(-fabsf(a))) + 0.001f;
        }
    }
}

// ---------------------------------------------------------------------------
extern "C" void kernel_launch(void* const* d_in, const int* in_sizes, int n_in,
                              void* d_out, int out_size, void* d_ws, size_t ws_size,
                              hipStream_t stream) {
    (void)in_sizes; (void)n_in; (void)out_size; (void)ws_size;
    const float* x = (const float*)d_in[0];
    const float* sn = (const float*)d_in[1];
    const float* node = (const float*)d_in[2];
    const float* W[13];
    const float* Bs[13];
    for (int i = 0; i < 13; ++i) {
        W[i] = (const float*)d_in[3 + 2 * i];
        Bs[i] = (const float*)d_in[4 + 2 * i];
    }
    float* out = (float*)d_out;

    char* ws = (char*)d_ws;
    int* knn = (int*)(ws + 0);                 //    73,728 (fallback only)
    u16* Wbf = (u16*)(ws + 73728);             // 2,396,160
    u16* h   = (u16*)(ws + 2469888);           //   524,288 (2048 x 128)

    WConvArgs wa;
    for (int w = 0; w < 12; ++w) wa.src[w] = W[w];

    const float* w3 = W[12];
    void* args[] = {
        (void*)&x, (void*)&sn, (void*)&node, (void*)&wa,
        (void*)&Wbf, (void*)&h,
        (void*)&Bs[0], (void*)&Bs[1], (void*)&Bs[2], (void*)&Bs[3], (void*)&Bs[4],
        (void*)&Bs[5], (void*)&Bs[6], (void*)&Bs[7], (void*)&Bs[8], (void*)&Bs[9],
        (void*)&Bs[10], (void*)&Bs[11], (void*)&w3, (void*)&Bs[12],
        (void*)&out
    };
    hipError_t err = hipLaunchCooperativeKernel(
        (const void*)mega_kernel, dim3(256), dim3(512), args, 0, stream);

    if (err != hipSuccess) {
        // fallback: proven 3-kernel pipeline (round-5)
        prep_kernel<<<5192, 256, 0, stream>>>(node, knn, wa, Wbf);
        fused_stage1_kernel<<<2048, 256, 0, stream>>>(x, sn, node, Wbf,
                                                      Bs[0], Bs[1], Bs[2], Bs[3], Bs[4], h);
        fused_stage23_kernel<<<256, 512, 0, stream>>>(node, h, knn, Wbf,
                                                      Bs[5], Bs[6], Bs[7], Bs[8], Bs[9],
                                                      Bs[10], Bs[11], W[12], Bs[12], out);
    }
}

// Round 7
// 232.611 us; speedup vs baseline: 1.7573x; 1.7573x over previous
//
#include <hip/hip_runtime.h>

typedef unsigned short u16;
typedef unsigned int u32;
typedef __bf16 bf16x8 __attribute__((ext_vector_type(8)));
typedef float floatx4 __attribute__((ext_vector_type(4)));
typedef unsigned short u16x8 __attribute__((ext_vector_type(8)));
typedef unsigned int u32x4 __attribute__((ext_vector_type(4)));

static constexpr int B_ = 4;
static constexpr int N_ = 16384;
static constexpr int M_ = 512;

__device__ __forceinline__ u16 f2bf(float f) {
    u32 u = __float_as_uint(f);
    u32 r = (u + 0x7fffu + ((u >> 16) & 1u)) >> 16;
    return (u16)r;
}
__device__ __forceinline__ float bf2f(u16 x) {
    return __uint_as_float(((u32)x) << 16);
}
__device__ __forceinline__ u32 pack2(float a, float b) {
    return (u32)f2bf(a) | ((u32)f2bf(b) << 16);
}

struct WConvArgs { const float* src[12]; };

// ---------------------------------------------------------------------------
// prep_kernel: blocks [0,512) knn (4 nodes/block); [512,5192) weight
// fp32->bf16 conversion. Ball query lives in fused_stage1.
// ---------------------------------------------------------------------------
__global__ __launch_bounds__(256) void prep_kernel(
    const float* __restrict__ node, int* __restrict__ knn,
    WConvArgs wa, u16* __restrict__ Wbf) {
    int bid = blockIdx.x;
    int tid = threadIdx.x, wave = tid >> 6, lane = tid & 63;

    if (bid < 512) {
        // ---- knn: wave handles node bid*4 + wave ----
        int bm = bid * 4 + wave;
        int b = bm >> 9, m = bm & 511;
        const float* nb = node + (size_t)b * 3 * M_;
        float nx = nb[m], ny = nb[M_ + m], nz = nb[2 * M_ + m];
        float aa = nx * nx + ny * ny + nz * nz;
        float dist[8];
        int didx[8];
#pragma unroll
        for (int i = 0; i < 8; ++i) {
            int n = lane + i * 64;
            float px = nb[n], py = nb[M_ + n], pz = nb[2 * M_ + n];
            float bb = px * px + py * py + pz * pz;
            float ab = nx * px + ny * py + nz * pz;
            dist[i] = aa + bb - 2.0f * ab;
            didx[i] = n;
        }
        for (int r = 0; r < 9; ++r) {
            float bv = dist[0]; int bi = didx[0]; int bslot = 0;
#pragma unroll
            for (int i = 1; i < 8; ++i) {
                if (dist[i] < bv || (dist[i] == bv && didx[i] < bi)) {
                    bv = dist[i]; bi = didx[i]; bslot = i;
                }
            }
            float rv = bv; int ri = bi;
            for (int off = 32; off > 0; off >>= 1) {
                float ov = __shfl_down(rv, off);
                int   oi = __shfl_down(ri, off);
                if (ov < rv || (ov == rv && oi < ri)) { rv = ov; ri = oi; }
            }
            ri = __shfl(ri, 0);
            if (lane == 0) knn[(size_t)bm * 9 + r] = ri;
            if (bi == ri) dist[bslot] = 3.0e38f;
        }
    } else {
        // ---- weight conversion ----
        const int CI[12] = {6, 64, 64, 128, 128, 131, 256, 256, 512, 512, 640, 512};
        const int KP[12] = {32, 64, 64, 128, 128, 160, 256, 256, 512, 512, 640, 512};
        const int OFF[13] = {0, 2048, 6144, 10240, 26624, 43008, 83968, 149504,
                             215040, 477184, 739328, 1067008, 1198080};
        int e = (bid - 512) * 256 + tid;
        int w = 0;
        while (e >= OFF[w + 1]) ++w;
        int local = e - OFF[w];
        int kp = KP[w];
        int co = local / kp, k = local - co * kp;
        float v = 0.0f;
        if (w == 5) {   // knnb1 K-layout: 0..2 coords, 8..135 feat1
            if (k < 3) v = wa.src[5][(size_t)co * 131 + k];
            else if (k >= 8 && k < 136) v = wa.src[5][(size_t)co * 131 + (k - 5)];
        } else if (k < CI[w]) {
            v = wa.src[w][(size_t)co * CI[w] + k];
        }
        Wbf[e] = f2bf(v);
    }
}

// ---------------------------------------------------------------------------
// Fused stage 1: ONE node per block, 2048 blocks, 256 threads (4 waves),
// 4 blocks/CU. Ball query split 4-ways across waves.
// ---------------------------------------------------------------------------
static constexpr int RS = 136;

__device__ __forceinline__ bf16x8 ldsA(const u16* act, int rf, int l15, int quad, int ks) {
    return *(const bf16x8*)(act + (rf * 16 + l15) * RS + ks * 32 + quad * 8);
}
__device__ __forceinline__ bf16x8 ldW(const u16* W, int ks, int l15, int quad, int kstride) {
    return *(const bf16x8*)(W + (size_t)l15 * kstride + ks * 32 + quad * 8);
}

__global__ __launch_bounds__(256, 4) void fused_stage1_kernel(
    const float* __restrict__ x, const float* __restrict__ sn,
    const float* __restrict__ node,
    const u16* __restrict__ Wbf,
    const float* __restrict__ b1, const float* __restrict__ b2,
    const float* __restrict__ b3, const float* __restrict__ b4,
    const float* __restrict__ b5, u16* __restrict__ h) {
    __shared__ __align__(16) u16 act[64 * RS];   // 17,408 B
    __shared__ __align__(16) u16 mv[64];
    __shared__ int sidx[4][64];
    __shared__ int scnt[4];
    int bm = blockIdx.x;               // 0..2047
    int b = bm >> 9, m = bm & 511;
    int tid = threadIdx.x, wave = tid >> 6, lane = tid & 63;
    int quad = lane >> 4, l15 = lane & 15;

    {   // ---- ball query: 4 waves split the 16K points, 4096 each ----
        const float* xb = x + (size_t)b * 3 * N_;
        float nx = node[((size_t)b * 3 + 0) * M_ + m];
        float ny = node[((size_t)b * 3 + 1) * M_ + m];
        float nz = node[((size_t)b * 3 + 2) * M_ + m];
        float aa = nx * nx + ny * ny + nz * nz;
        int cnt = 0;
        int base = wave * 4096;
#pragma unroll 1
        for (int n0 = base; n0 < base + 4096; n0 += 256) {
            float px[4], py[4], pz[4];
#pragma unroll
            for (int i = 0; i < 4; ++i) {
                int n = n0 + i * 64 + lane;
                px[i] = xb[n]; py[i] = xb[N_ + n]; pz[i] = xb[2 * N_ + n];
            }
#pragma unroll
            for (int i = 0; i < 4; ++i) {
                float bb = px[i] * px[i] + py[i] * py[i] + pz[i] * pz[i];
                float d = aa + bb - 2.0f * (nx * px[i] + ny * py[i] + nz * pz[i]);
                bool inb = d < 4.0f;
                unsigned long long mask = __ballot(inb);
                if (inb && cnt < 64) {
                    int pos = cnt + __popcll(mask & ((1ull << lane) - 1ull));
                    if (pos < 64) sidx[wave][pos] = n0 + i * 64 + lane;
                }
                cnt += __popcll(mask);
            }
            if (cnt >= 64) break;   // wave-uniform
        }
        if (lane == 0) scnt[wave] = cnt;
    }
    __syncthreads();

    if (tid < 64) {   // combine + gather row tid
        int total = scnt[0] + scnt[1] + scnt[2] + scnt[3];
        int j = 0;
        if (total > 0) {
            int lim = total < 64 ? total : 64;
            int slot = tid < lim ? tid : 0;
            int w = 0, pre = 0;
            while (w < 3 && slot >= pre + scnt[w]) { pre += scnt[w]; ++w; }
            j = sidx[w][slot - pre];
        }
        const float* xb = x + (size_t)b * 3 * N_;
        const float* sb = sn + (size_t)b * 3 * N_;
        float c0 = xb[j]          - node[((size_t)b * 3 + 0) * M_ + m];
        float c1 = xb[N_ + j]     - node[((size_t)b * 3 + 1) * M_ + m];
        float c2 = xb[2 * N_ + j] - node[((size_t)b * 3 + 2) * M_ + m];
        float s0 = sb[j], s1 = sb[N_ + j], s2 = sb[2 * N_ + j];
        u16* r = act + tid * RS;
        *(u32*)(r)     = pack2(c0, c1);
        *(u32*)(r + 2) = pack2(c2, s0);
        *(u32*)(r + 4) = pack2(s1, s2);
        *(u32*)(r + 6) = 0u;
        u32x4* z = (u32x4*)(r + 8);
        z[0] = (u32x4){0u, 0u, 0u, 0u};
        z[1] = (u32x4){0u, 0u, 0u, 0u};
        z[2] = (u32x4){0u, 0u, 0u, 0u};
    }
    __syncthreads();

    {   // conv1: K=32 (6 used), co 64 (wave owns 16), RF=4
        const u16* Wp = Wbf + (size_t)(wave * 16) * 32;
        bf16x8 bw = ldW(Wp, 0, l15, quad, 32);
        floatx4 c[4];
#pragma unroll
        for (int rf = 0; rf < 4; ++rf) {
            bf16x8 a = ldsA(act, rf, l15, quad, 0);
            c[rf] = __builtin_amdgcn_mfma_f32_16x16x32_bf16(a, bw, (floatx4){0.f,0.f,0.f,0.f}, 0, 0, 0);
        }
        float bias = b1[wave * 16 + l15];
        __syncthreads();
#pragma unroll
        for (int rf = 0; rf < 4; ++rf)
#pragma unroll
            for (int r = 0; r < 4; ++r)
                act[(rf * 16 + quad * 4 + r) * RS + wave * 16 + l15] = f2bf(fmaxf(c[rf][r] + bias, 0.0f));
        __syncthreads();
    }

    const int WOFF23[2] = {2048, 6144};
    const float* bp23[2] = {b2, b3};
#pragma unroll 1
    for (int cv = 0; cv < 2; ++cv) {   // conv2 / conv3: K=64, co 64, RF=4
        const u16* Wp = Wbf + WOFF23[cv] + (size_t)(wave * 16) * 64;
        bf16x8 bw0 = ldW(Wp, 0, l15, quad, 64);
        bf16x8 bw1 = ldW(Wp, 1, l15, quad, 64);
        floatx4 c[4] = {};
#pragma unroll
        for (int ks = 0; ks < 2; ++ks)
#pragma unroll
            for (int rf = 0; rf < 4; ++rf) {
                bf16x8 a = ldsA(act, rf, l15, quad, ks);
                c[rf] = __builtin_amdgcn_mfma_f32_16x16x32_bf16(a, ks ? bw1 : bw0, c[rf], 0, 0, 0);
            }
        float bias = bp23[cv][wave * 16 + l15];
        float mx = 0.0f;
#pragma unroll
        for (int rf = 0; rf < 4; ++rf)
#pragma unroll
            for (int r = 0; r < 4; ++r)
                mx = fmaxf(mx, fmaxf(c[rf][r] + bias, 0.0f));
        __syncthreads();
#pragma unroll
        for (int rf = 0; rf < 4; ++rf)
#pragma unroll
            for (int r = 0; r < 4; ++r)
                act[(rf * 16 + quad * 4 + r) * RS + wave * 16 + l15] = f2bf(fmaxf(c[rf][r] + bias, 0.0f));
        if (cv == 1) {
            mx = fmaxf(mx, __shfl_xor(mx, 16));
            mx = fmaxf(mx, __shfl_xor(mx, 32));
            if (quad == 0) mv[wave * 16 + l15] = f2bf(mx);
        }
        __syncthreads();
    }

    {   // conv4: K=128 ([conv3 | rowmax]), co 128 (wave owns 32), RF=4
        const u16* Wp = Wbf + 10240 + (size_t)(wave * 32) * 128;
        bf16x8 bw[2][4];
#pragma unroll
        for (int cf = 0; cf < 2; ++cf)
#pragma unroll
            for (int ks = 0; ks < 4; ++ks)
                bw[cf][ks] = ldW(Wp + (size_t)cf * 16 * 128, ks, l15, quad, 128);
        floatx4 c[4][2] = {};
#pragma unroll
        for (int ks = 0; ks < 4; ++ks) {
            bf16x8 amv;
            if (ks >= 2) amv = *(const bf16x8*)(&mv[(ks - 2) * 32 + quad * 8]);
#pragma unroll
            for (int rf = 0; rf < 4; ++rf) {
                bf16x8 a = (ks < 2) ? ldsA(act, rf, l15, quad, ks) : amv;
#pragma unroll
                for (int cf = 0; cf < 2; ++cf)
                    c[rf][cf] = __builtin_amdgcn_mfma_f32_16x16x32_bf16(a, bw[cf][ks], c[rf][cf], 0, 0, 0);
            }
        }
        float bias[2];
#pragma unroll
        for (int cf = 0; cf < 2; ++cf) bias[cf] = b4[wave * 32 + cf * 16 + l15];
        __syncthreads();
#pragma unroll
        for (int rf = 0; rf < 4; ++rf)
#pragma unroll
            for (int cf = 0; cf < 2; ++cf)
#pragma unroll
                for (int r = 0; r < 4; ++r)
                    act[(rf * 16 + quad * 4 + r) * RS + wave * 32 + cf * 16 + l15] =
                        f2bf(fmaxf(c[rf][cf][r] + bias[cf], 0.0f));
        __syncthreads();
    }

    {   // conv5 + per-node maxpool -> h[bm][0:128] (h stride 128)
        const u16* Wp = Wbf + 26624 + (size_t)(wave * 32) * 128;
        bf16x8 bw[2][4];
#pragma unroll
        for (int cf = 0; cf < 2; ++cf)
#pragma unroll
            for (int ks = 0; ks < 4; ++ks)
                bw[cf][ks] = ldW(Wp + (size_t)cf * 16 * 128, ks, l15, quad, 128);
        floatx4 c[4][2] = {};
#pragma unroll
        for (int ks = 0; ks < 4; ++ks)
#pragma unroll
            for (int rf = 0; rf < 4; ++rf) {
                bf16x8 a = ldsA(act, rf, l15, quad, ks);
#pragma unroll
                for (int cf = 0; cf < 2; ++cf)
                    c[rf][cf] = __builtin_amdgcn_mfma_f32_16x16x32_bf16(a, bw[cf][ks], c[rf][cf], 0, 0, 0);
            }
#pragma unroll
        for (int cf = 0; cf < 2; ++cf) {
            float bias = b5[wave * 32 + cf * 16 + l15];
            float mx = 0.0f;
#pragma unroll
            for (int rf = 0; rf < 4; ++rf)
#pragma unroll
                for (int r = 0; r < 4; ++r)
                    mx = fmaxf(mx, fmaxf(c[rf][cf][r] + bias, 0.0f));
            mx = fmaxf(mx, __shfl_xor(mx, 16));
            mx = fmaxf(mx, __shfl_xor(mx, 32));
            if (quad == 0)
                h[(size_t)bm * 128 + wave * 32 + cf * 16 + l15] = f2bf(mx);
        }
    }
}

// ---------------------------------------------------------------------------
// In-LDS in-place conv. PF = weight prefetch ring size (power of 2).
// ---------------------------------------------------------------------------
template <int KS, int CF, int RF, int PF, int RSx>
__device__ __forceinline__ void conv_inplace(u16* act, const u16* __restrict__ W0, int KP,
                                             const float* __restrict__ bias, int cb,
                                             int l15, int quad) {
    floatx4 acc[RF][CF];
#pragma unroll
    for (int rf = 0; rf < RF; ++rf)
#pragma unroll
        for (int cf = 0; cf < CF; ++cf) acc[rf][cf] = (floatx4){0.f, 0.f, 0.f, 0.f};

    bf16x8 bw[PF][CF];
#pragma unroll
    for (int p = 0; p < PF - 1; ++p)
        if (p < KS)
#pragma unroll
            for (int cf = 0; cf < CF; ++cf)
                bw[p][cf] = *(const bf16x8*)(W0 + (size_t)(cb + cf * 16 + l15) * KP +
                                             p * 32 + quad * 8);

#pragma unroll
    for (int ks = 0; ks < KS; ++ks) {
        if (ks + PF - 1 < KS) {
#pragma unroll
            for (int cf = 0; cf < CF; ++cf)
                bw[(ks + PF - 1) & (PF - 1)][cf] =
                    *(const bf16x8*)(W0 + (size_t)(cb + cf * 16 + l15) * KP +
                                     (ks + PF - 1) * 32 + quad * 8);
        }
#pragma unroll
        for (int rf = 0; rf < RF; ++rf) {
            bf16x8 a = *(const bf16x8*)(act + (rf * 16 + l15) * RSx + ks * 32 + quad * 8);
#pragma unroll
            for (int cf = 0; cf < CF; ++cf)
                acc[rf][cf] = __builtin_amdgcn_mfma_f32_16x16x32_bf16(a, bw[ks & (PF - 1)][cf], acc[rf][cf], 0, 0, 0);
        }
    }
    __syncthreads();   // all waves' reads complete before in-place writes
#pragma unroll
    for (int cf = 0; cf < CF; ++cf) {
        float bs = bias[cb + cf * 16 + l15];
#pragma unroll
        for (int rf = 0; rf < RF; ++rf)
#pragma unroll
            for (int r = 0; r < 4; ++r)
                act[(rf * 16 + quad * 4 + r) * RSx + cb + cf * 16 + l15] =
                    f2bf(fmaxf(acc[rf][cf][r] + bs, 0.0f));
    }
    __syncthreads();
}

// ---------------------------------------------------------------------------
// Fused stage 2+3: one block per 8 nodes, 256 blocks x 1024 threads
// (16 waves = 4 waves/SIMD, 50% occupancy). Same 8-node tile and LDS as the
// proven 512-thread version; co split 16 ways (CF halves) so per-wave regs
// ~45 VGPR + 40 AGPR << the 128 cap 16-wave residency requires. Weight L2
// traffic unchanged (co-partition: each weight element loaded once/block).
// Doubled wave pool per SIMD hides the weight-load latency that kept
// MfmaUtil at 14.5% with 2 waves/SIMD.
// ---------------------------------------------------------------------------
static constexpr int RS2 = 520;
static constexpr int RS3 = 648;

__global__ __launch_bounds__(1024, 4) void fused_stage23_kernel(
    const float* __restrict__ node, const u16* __restrict__ h,
    const int* __restrict__ knn, const u16* __restrict__ Wbf,
    const float* __restrict__ bb1, const float* __restrict__ bb2,
    const float* __restrict__ bb3, const float* __restrict__ ba1,
    const float* __restrict__ ba2,
    const float* __restrict__ bm1, const float* __restrict__ bm2,
    const float* __restrict__ w3, const float* __restrict__ b3,
    float* __restrict__ out) {
    __shared__ __align__(16) u16 act[80 * RS2 + 16 * RS3];   // 103,936 B
    u16* mlpT = act + 80 * RS2;
    int blk = blockIdx.x;              // 0..255
    int node0 = blk * 8;
    int b = node0 >> 9;
    int tid = threadIdx.x, wave = tid >> 6, lane = tid & 63;
    int quad = lane >> 4, l15 = lane & 15;
    (void)lane;

    for (int e = tid; e < 80 * 20; e += 1024)
        *(u16x8*)(act + (e / 20) * RS2 + (e % 20) * 8) = (u16x8){0,0,0,0,0,0,0,0};
    __syncthreads();
    for (int e = tid; e < 72 * 3; e += 1024) {
        int r = e / 3, c = e - r * 3;
        int nodei = node0 + r / 9;
        int j = knn[(size_t)nodei * 9 + (r % 9)];
        float v = node[((size_t)b * 3 + c) * M_ + j] - node[((size_t)b * 3 + c) * M_ + (nodei & 511)];
        act[r * RS2 + c] = f2bf(v);
    }
    for (int e = tid; e < 72 * 16; e += 1024) {
        int r = e >> 4, s = e & 15;
        int nodei = node0 + r / 9;
        int j = knn[(size_t)nodei * 9 + (r % 9)];
        *(u16x8*)(act + r * RS2 + 8 + s * 8) =
            *(const u16x8*)(h + (size_t)(b * 512 + j) * 128 + s * 8);
    }
    __syncthreads();

    // co 256 over 16 waves -> CF=1 (wave owns 16)
    conv_inplace<5, 1, 5, 2, RS2>(act, Wbf + 43008, 160, bb1, wave * 16, l15, quad);
    conv_inplace<8, 1, 5, 2, RS2>(act, Wbf + 83968, 256, bb2, wave * 16, l15, quad);
    conv_inplace<8, 1, 5, 2, RS2>(act, Wbf + 149504, 256, bb3, wave * 16, l15, quad);

    // per-node maxpool over 9 neighbor rows, replicated into cols 256..511
    for (int e = tid; e < 8 * 32; e += 1024) {
        int li = e >> 5, s = e & 31;
        int r0 = li * 9;
        float mx[8];
#pragma unroll
        for (int i = 0; i < 8; ++i) mx[i] = -3.0e38f;
#pragma unroll
        for (int kk = 0; kk < 9; ++kk) {
            u16x8 v = *(const u16x8*)(act + (r0 + kk) * RS2 + s * 8);
#pragma unroll
            for (int i = 0; i < 8; ++i) mx[i] = fmaxf(mx[i], bf2f(v[i]));
        }
        u16x8 o;
#pragma unroll
        for (int i = 0; i < 8; ++i) o[i] = f2bf(mx[i]);
#pragma unroll
        for (int kk = 0; kk < 9; ++kk)
            *(u16x8*)(act + (r0 + kk) * RS2 + 256 + s * 8) = o;
    }
    __syncthreads();

    // co 512 over 16 waves -> CF=2 (wave owns 32)
    conv_inplace<16, 2, 5, 2, RS2>(act, Wbf + 215040, 512, ba1, wave * 32, l15, quad);
    conv_inplace<16, 2, 5, 2, RS2>(act, Wbf + 477184, 512, ba2, wave * 32, l15, quad);

    // ---- stage3 tail: build mlp input tile [16 x 640] in mlpT ----
    for (int e = tid; e < 8 * 64; e += 1024) {
        int li = e >> 6, s = e & 63;
        int r0 = li * 9;
        float mx[8];
#pragma unroll
        for (int i = 0; i < 8; ++i) mx[i] = -3.0e38f;
#pragma unroll
        for (int kk = 0; kk < 9; ++kk) {
            u16x8 v = *(const u16x8*)(act + (r0 + kk) * RS2 + s * 8);
#pragma unroll
            for (int i = 0; i < 8; ++i) mx[i] = fmaxf(mx[i], bf2f(v[i]));
        }
        u16x8 o;
#pragma unroll
        for (int i = 0; i < 8; ++i) o[i] = f2bf(mx[i]);
        *(u16x8*)(mlpT + li * RS3 + 128 + s * 8) = o;
    }
    // feat1 = h[node][0:128] (written by stage1)
    for (int e = tid; e < 8 * 16; e += 1024) {
        int li = e >> 4, s = e & 15;
        *(u16x8*)(mlpT + li * RS3 + s * 8) =
            *(const u16x8*)(h + (size_t)(node0 + li) * 128 + s * 8);
    }
    // zero pad rows 8..15
    for (int e = tid; e < 8 * 80; e += 1024) {
        int r = e / 80, seg = e - r * 80;
        *(u16x8*)(mlpT + (8 + r) * RS3 + seg * 8) = (u16x8){0,0,0,0,0,0,0,0};
    }
    __syncthreads();

    // mlp1 co 512 -> CF=2; mlp2 co 256 -> CF=1
    conv_inplace<20, 2, 1, 2, RS3>(mlpT, Wbf + 739328, 640, bm1, wave * 32, l15, quad);
    conv_inplace<16, 1, 1, 2, RS3>(mlpT, Wbf + 1067008, 512, bm2, wave * 16, l15, quad);

    if (tid < 32) {
        int li = tid >> 2, oc = tid & 3;
        const u16* row = mlpT + li * RS3;
        const float* wrow = w3 + oc * 256;
        float a = 0.0f;
        for (int c = 0; c < 256; c += 4) {
            a += bf2f(row[c]) * wrow[c];
            a += bf2f(row[c + 1]) * wrow[c + 1];
            a += bf2f(row[c + 2]) * wrow[c + 2];
            a += bf2f(row[c + 3]) * wrow[c + 3];
        }
        a += b3[oc];
        int nodei = node0 + li;
        int bo = nodei >> 9, m = nodei & 511;
        if (oc < 3) {
            float nv = node[((size_t)bo * 3 + oc) * M_ + m];
            out[((size_t)bo * 3 + oc) * M_ + m] = nv;
            out[6144 + ((size_t)bo * 3 + oc) * M_ + m] = nv + a;
        } else {
            out[12288 + nodei] = fmaxf(a, 0.0f) + log1pf(expf(-fabsf(a))) + 0.001f;
        }
    }
}

// ---------------------------------------------------------------------------
extern "C" void kernel_launch(void* const* d_in, const int* in_sizes, int n_in,
                              void* d_out, int out_size, void* d_ws, size_t ws_size,
                              hipStream_t stream) {
    (void)in_sizes; (void)n_in; (void)out_size; (void)ws_size;
    const float* x = (const float*)d_in[0];
    const float* sn = (const float*)d_in[1];
    const float* node = (const float*)d_in[2];
    const float* W[13];
    const float* Bs[13];
    for (int i = 0; i < 13; ++i) {
        W[i] = (const float*)d_in[3 + 2 * i];
        Bs[i] = (const float*)d_in[4 + 2 * i];
    }
    float* out = (float*)d_out;

    char* ws = (char*)d_ws;
    int* knn = (int*)(ws + 0);                 //    73,728
    u16* Wbf = (u16*)(ws + 73728);             // 2,396,160
    u16* h   = (u16*)(ws + 2469888);           //   524,288 (2048 x 128)

    WConvArgs wa;
    for (int w = 0; w < 12; ++w) wa.src[w] = W[w];

    prep_kernel<<<5192, 256, 0, stream>>>(node, knn, wa, Wbf);

    fused_stage1_kernel<<<2048, 256, 0, stream>>>(x, sn, node, Wbf,
                                                  Bs[0], Bs[1], Bs[2], Bs[3], Bs[4], h);
    fused_stage23_kernel<<<256, 1024, 0, stream>>>(node, h, knn, Wbf,
                                                   Bs[5], Bs[6], Bs[7], Bs[8], Bs[9],
                                                   Bs[10], Bs[11], W[12], Bs[12], out);
}

// Round 10
// 222.097 us; speedup vs baseline: 1.8405x; 1.0473x over previous
//
#include <hip/hip_runtime.h>

typedef unsigned short u16;
typedef unsigned int u32;
typedef __bf16 bf16x8 __attribute__((ext_vector_type(8)));
typedef float floatx4 __attribute__((ext_vector_type(4)));
typedef unsigned short u16x8 __attribute__((ext_vector_type(8)));
typedef unsigned int u32x4 __attribute__((ext_vector_type(4)));

static constexpr int B_ = 4;
static constexpr int N_ = 16384;
static constexpr int M_ = 512;

__device__ __forceinline__ u16 f2bf(float f) {
    u32 u = __float_as_uint(f);
    u32 r = (u + 0x7fffu + ((u >> 16) & 1u)) >> 16;
    return (u16)r;
}
__device__ __forceinline__ float bf2f(u16 x) {
    return __uint_as_float(((u32)x) << 16);
}
__device__ __forceinline__ u32 pack2(float a, float b) {
    return (u32)f2bf(a) | ((u32)f2bf(b) << 16);
}

struct WConvArgs { const float* src[12]; };

// ---------------------------------------------------------------------------
// prep_kernel: blocks [0,2048) ball query; [2048,2560) knn (4 nodes/block);
// [2560,7240) weight fp32->bf16 conversion. All parts independent.
// (Round-2 champion configuration, byte-for-byte.)
// ---------------------------------------------------------------------------
__global__ __launch_bounds__(256) void prep_kernel(
    const float* __restrict__ x, const float* __restrict__ node,
    int* __restrict__ idx, int* __restrict__ knn,
    WConvArgs wa, u16* __restrict__ Wbf) {
    int bid = blockIdx.x;
    int tid = threadIdx.x, wave = tid >> 6, lane = tid & 63;

    if (bid < 2048) {
        // ---- ball query: 4 waves per (b,m); 4-iter batched loads ----
        int bm = bid;
        int b = bm >> 9, m = bm & 511;
        __shared__ int sidx[4][64];
        __shared__ int scnt[4];
        const float* xb = x + (size_t)b * 3 * N_;
        float nx = node[((size_t)b * 3 + 0) * M_ + m];
        float ny = node[((size_t)b * 3 + 1) * M_ + m];
        float nz = node[((size_t)b * 3 + 2) * M_ + m];
        float aa = nx * nx + ny * ny + nz * nz;
        int cnt = 0;
        int base = wave * 4096;
        for (int n0 = base; n0 < base + 4096; n0 += 256) {
            float px[4], py[4], pz[4];
#pragma unroll
            for (int i = 0; i < 4; ++i) {
                int n = n0 + i * 64 + lane;
                px[i] = xb[n]; py[i] = xb[N_ + n]; pz[i] = xb[2 * N_ + n];
            }
#pragma unroll
            for (int i = 0; i < 4; ++i) {
                float bb = px[i] * px[i] + py[i] * py[i] + pz[i] * pz[i];
                float d = aa + bb - 2.0f * (nx * px[i] + ny * py[i] + nz * pz[i]);
                bool inb = d < 4.0f;
                unsigned long long mask = __ballot(inb);
                if (inb && cnt < 64) {
                    int pos = cnt + __popcll(mask & ((1ull << lane) - 1ull));
                    if (pos < 64) sidx[wave][pos] = n0 + i * 64 + lane;
                }
                cnt += __popcll(mask);
            }
            if (cnt >= 64) break;   // wave-uniform; truncated counts stay >=64
        }
        if (lane == 0) scnt[wave] = cnt;
        __syncthreads();
        if (tid < 64) {
            int total = scnt[0] + scnt[1] + scnt[2] + scnt[3];
            int v = 0;
            if (total > 0) {
                int lim = total < 64 ? total : 64;
                int slot = tid < lim ? tid : 0;
                int w = 0, pre = 0;
                while (w < 3 && slot >= pre + scnt[w]) { pre += scnt[w]; ++w; }
                v = sidx[w][slot - pre];
            }
            idx[(size_t)bm * 64 + tid] = v;
        }
    } else if (bid < 2560) {
        // ---- knn: wave handles node (bid-2048)*4 + wave ----
        int bm = (bid - 2048) * 4 + wave;
        int b = bm >> 9, m = bm & 511;
        const float* nb = node + (size_t)b * 3 * M_;
        float nx = nb[m], ny = nb[M_ + m], nz = nb[2 * M_ + m];
        float aa = nx * nx + ny * ny + nz * nz;
        float dist[8];
        int didx[8];
#pragma unroll
        for (int i = 0; i < 8; ++i) {
            int n = lane + i * 64;
            float px = nb[n], py = nb[M_ + n], pz = nb[2 * M_ + n];
            float bb = px * px + py * py + pz * pz;
            float ab = nx * px + ny * py + nz * pz;
            dist[i] = aa + bb - 2.0f * ab;
            didx[i] = n;
        }
        for (int r = 0; r < 9; ++r) {
            float bv = dist[0]; int bi = didx[0]; int bslot = 0;
#pragma unroll
            for (int i = 1; i < 8; ++i) {
                if (dist[i] < bv || (dist[i] == bv && didx[i] < bi)) {
                    bv = dist[i]; bi = didx[i]; bslot = i;
                }
            }
            float rv = bv; int ri = bi;
            for (int off = 32; off > 0; off >>= 1) {
                float ov = __shfl_down(rv, off);
                int   oi = __shfl_down(ri, off);
                if (ov < rv || (ov == rv && oi < ri)) { rv = ov; ri = oi; }
            }
            ri = __shfl(ri, 0);
            if (lane == 0) knn[(size_t)bm * 9 + r] = ri;
            if (bi == ri) dist[bslot] = 3.0e38f;
        }
    } else {
        // ---- weight conversion ----
        const int CI[12] = {6, 64, 64, 128, 128, 131, 256, 256, 512, 512, 640, 512};
        const int KP[12] = {32, 64, 64, 128, 128, 160, 256, 256, 512, 512, 640, 512};
        const int OFF[13] = {0, 2048, 6144, 10240, 26624, 43008, 83968, 149504,
                             215040, 477184, 739328, 1067008, 1198080};
        int e = (bid - 2560) * 256 + tid;
        int w = 0;
        while (e >= OFF[w + 1]) ++w;
        int local = e - OFF[w];
        int kp = KP[w];
        int co = local / kp, k = local - co * kp;
        float v = 0.0f;
        if (w == 5) {   // knnb1 K-layout: 0..2 coords, 8..135 feat1
            if (k < 3) v = wa.src[5][(size_t)co * 131 + k];
            else if (k >= 8 && k < 136) v = wa.src[5][(size_t)co * 131 + (k - 5)];
        } else if (k < CI[w]) {
            v = wa.src[w][(size_t)co * CI[w] + k];
        }
        Wbf[e] = f2bf(v);
    }
}

// ---------------------------------------------------------------------------
// Fused stage 1: one block per 4 nodes (256 rows, RF=16), 256 threads,
// 2 blocks/CU. (Round-2 champion, RS=136 — unchanged.)
// ---------------------------------------------------------------------------
static constexpr int RS = 136;

__device__ __forceinline__ bf16x8 ldsA(const u16* act, int rf, int l15, int quad, int ks) {
    return *(const bf16x8*)(act + (rf * 16 + l15) * RS + ks * 32 + quad * 8);
}
__device__ __forceinline__ bf16x8 ldW(const u16* W, int ks, int l15, int quad, int kstride) {
    return *(const bf16x8*)(W + (size_t)l15 * kstride + ks * 32 + quad * 8);
}

__global__ __launch_bounds__(256, 2) void fused_stage1_kernel(
    const float* __restrict__ x, const float* __restrict__ sn,
    const float* __restrict__ node, const int* __restrict__ idx,
    const u16* __restrict__ Wbf,
    const float* __restrict__ b1, const float* __restrict__ b2,
    const float* __restrict__ b3, const float* __restrict__ b4,
    const float* __restrict__ b5, u16* __restrict__ h) {
    __shared__ __align__(16) u16 act[256 * RS];   // 69,632 B
    __shared__ __align__(16) u16 mv[4][64];
    int blk = blockIdx.x;              // 0..511
    int bm0 = blk * 4;
    int tid = threadIdx.x, wave = tid >> 6, lane = tid & 63;
    int quad = lane >> 4, l15 = lane & 15;

    {   // gather 4 nodes x 64 neighbors: one full row per thread
        int row = tid;
        int bm = bm0 + (row >> 6);
        int b = bm >> 9, m = bm & 511;
        int j = idx[(size_t)bm * 64 + (row & 63)];
        const float* xb = x + (size_t)b * 3 * N_;
        const float* sb = sn + (size_t)b * 3 * N_;
        float c0 = xb[j]          - node[((size_t)b * 3 + 0) * M_ + m];
        float c1 = xb[N_ + j]     - node[((size_t)b * 3 + 1) * M_ + m];
        float c2 = xb[2 * N_ + j] - node[((size_t)b * 3 + 2) * M_ + m];
        float s0 = sb[j], s1 = sb[N_ + j], s2 = sb[2 * N_ + j];
        u16* r = act + row * RS;
        *(u32*)(r)     = pack2(c0, c1);
        *(u32*)(r + 2) = pack2(c2, s0);
        *(u32*)(r + 4) = pack2(s1, s2);
        *(u32*)(r + 6) = 0u;
        u32x4* z = (u32x4*)(r + 8);
        z[0] = (u32x4){0u, 0u, 0u, 0u};
        z[1] = (u32x4){0u, 0u, 0u, 0u};
        z[2] = (u32x4){0u, 0u, 0u, 0u};
    }
    __syncthreads();

    {   // conv1: K=32 (6 used), co 64 (wave owns 16)
        const u16* Wp = Wbf + (size_t)(wave * 16) * 32;
        bf16x8 bw = ldW(Wp, 0, l15, quad, 32);
        floatx4 c[16];
#pragma unroll
        for (int rf = 0; rf < 16; ++rf) {
            bf16x8 a = ldsA(act, rf, l15, quad, 0);
            c[rf] = __builtin_amdgcn_mfma_f32_16x16x32_bf16(a, bw, (floatx4){0.f,0.f,0.f,0.f}, 0, 0, 0);
        }
        float bias = b1[wave * 16 + l15];
        __syncthreads();
#pragma unroll
        for (int rf = 0; rf < 16; ++rf)
#pragma unroll
            for (int r = 0; r < 4; ++r)
                act[(rf * 16 + quad * 4 + r) * RS + wave * 16 + l15] = f2bf(fmaxf(c[rf][r] + bias, 0.0f));
        __syncthreads();
    }

    const int WOFF23[2] = {2048, 6144};
    const float* bp23[2] = {b2, b3};
#pragma unroll 1
    for (int cv = 0; cv < 2; ++cv) {   // conv2 / conv3: K=64, co 64
        const u16* Wp = Wbf + WOFF23[cv] + (size_t)(wave * 16) * 64;
        bf16x8 bw0 = ldW(Wp, 0, l15, quad, 64);
        bf16x8 bw1 = ldW(Wp, 1, l15, quad, 64);
        floatx4 c[16] = {};
#pragma unroll
        for (int ks = 0; ks < 2; ++ks)
#pragma unroll
            for (int rf = 0; rf < 16; ++rf) {
                bf16x8 a = ldsA(act, rf, l15, quad, ks);
                c[rf] = __builtin_amdgcn_mfma_f32_16x16x32_bf16(a, ks ? bw1 : bw0, c[rf], 0, 0, 0);
            }
        float bias = bp23[cv][wave * 16 + l15];
        float mxN[4] = {0.0f, 0.0f, 0.0f, 0.0f};
#pragma unroll
        for (int rf = 0; rf < 16; ++rf)
#pragma unroll
            for (int r = 0; r < 4; ++r) {
                float v = fmaxf(c[rf][r] + bias, 0.0f);
                mxN[rf >> 2] = fmaxf(mxN[rf >> 2], v);
            }
        __syncthreads();
#pragma unroll
        for (int rf = 0; rf < 16; ++rf)
#pragma unroll
            for (int r = 0; r < 4; ++r)
                act[(rf * 16 + quad * 4 + r) * RS + wave * 16 + l15] = f2bf(fmaxf(c[rf][r] + bias, 0.0f));
        if (cv == 1) {
#pragma unroll
            for (int n = 0; n < 4; ++n) {
                float mx = mxN[n];
                mx = fmaxf(mx, __shfl_xor(mx, 16));
                mx = fmaxf(mx, __shfl_xor(mx, 32));
                if (quad == 0) mv[n][wave * 16 + l15] = f2bf(mx);
            }
        }
        __syncthreads();
    }

    {   // conv4: K=128 ([conv3 | per-node rowmax]), co 128 (wave owns 32)
        const u16* Wp = Wbf + 10240 + (size_t)(wave * 32) * 128;
        bf16x8 bw[2][4];
#pragma unroll
        for (int cf = 0; cf < 2; ++cf)
#pragma unroll
            for (int ks = 0; ks < 4; ++ks)
                bw[cf][ks] = ldW(Wp + (size_t)cf * 16 * 128, ks, l15, quad, 128);
        floatx4 c[16][2] = {};
#pragma unroll
        for (int ks = 0; ks < 4; ++ks)
#pragma unroll
            for (int rf = 0; rf < 16; ++rf) {
                bf16x8 a = (ks < 2) ? ldsA(act, rf, l15, quad, ks)
                                    : *(const bf16x8*)(&mv[rf >> 2][(ks - 2) * 32 + quad * 8]);
#pragma unroll
                for (int cf = 0; cf < 2; ++cf)
                    c[rf][cf] = __builtin_amdgcn_mfma_f32_16x16x32_bf16(a, bw[cf][ks], c[rf][cf], 0, 0, 0);
            }
        float bias[2];
#pragma unroll
        for (int cf = 0; cf < 2; ++cf) bias[cf] = b4[wave * 32 + cf * 16 + l15];
        __syncthreads();
#pragma unroll
        for (int rf = 0; rf < 16; ++rf)
#pragma unroll
            for (int cf = 0; cf < 2; ++cf)
#pragma unroll
                for (int r = 0; r < 4; ++r)
                    act[(rf * 16 + quad * 4 + r) * RS + wave * 32 + cf * 16 + l15] =
                        f2bf(fmaxf(c[rf][cf][r] + bias[cf], 0.0f));
        __syncthreads();
    }

    {   // conv5 + per-node maxpool -> h[bm][0:128]
        const u16* Wp = Wbf + 26624 + (size_t)(wave * 32) * 128;
        bf16x8 bw[2][4];
#pragma unroll
        for (int cf = 0; cf < 2; ++cf)
#pragma unroll
            for (int ks = 0; ks < 4; ++ks)
                bw[cf][ks] = ldW(Wp + (size_t)cf * 16 * 128, ks, l15, quad, 128);
        floatx4 c[16][2] = {};
#pragma unroll
        for (int ks = 0; ks < 4; ++ks)
#pragma unroll
            for (int rf = 0; rf < 16; ++rf) {
                bf16x8 a = ldsA(act, rf, l15, quad, ks);
#pragma unroll
                for (int cf = 0; cf < 2; ++cf)
                    c[rf][cf] = __builtin_amdgcn_mfma_f32_16x16x32_bf16(a, bw[cf][ks], c[rf][cf], 0, 0, 0);
            }
#pragma unroll
        for (int cf = 0; cf < 2; ++cf) {
            float bias = b5[wave * 32 + cf * 16 + l15];
            float mxN[4] = {0.0f, 0.0f, 0.0f, 0.0f};
#pragma unroll
            for (int rf = 0; rf < 16; ++rf)
#pragma unroll
                for (int r = 0; r < 4; ++r) {
                    float v = fmaxf(c[rf][cf][r] + bias, 0.0f);
                    mxN[rf >> 2] = fmaxf(mxN[rf >> 2], v);
                }
#pragma unroll
            for (int n = 0; n < 4; ++n) {
                float mx = mxN[n];
                mx = fmaxf(mx, __shfl_xor(mx, 16));
                mx = fmaxf(mx, __shfl_xor(mx, 32));
                if (quad == 0)
                    h[(size_t)(bm0 + n) * 640 + wave * 32 + cf * 16 + l15] = f2bf(mx);
            }
        }
    }
}

// ---------------------------------------------------------------------------
// In-LDS in-place conv. PF = weight prefetch ring size (power of 2).
// ---------------------------------------------------------------------------
template <int KS, int CF, int RF, int PF, int RSx>
__device__ __forceinline__ void conv_inplace(u16* act, const u16* __restrict__ W0, int KP,
                                             const float* __restrict__ bias, int cb,
                                             int l15, int quad) {
    floatx4 acc[RF][CF];
#pragma unroll
    for (int rf = 0; rf < RF; ++rf)
#pragma unroll
        for (int cf = 0; cf < CF; ++cf) acc[rf][cf] = (floatx4){0.f, 0.f, 0.f, 0.f};

    bf16x8 bw[PF][CF];
#pragma unroll
    for (int p = 0; p < PF - 1; ++p)
        if (p < KS)
#pragma unroll
            for (int cf = 0; cf < CF; ++cf)
                bw[p][cf] = *(const bf16x8*)(W0 + (size_t)(cb + cf * 16 + l15) * KP +
                                             p * 32 + quad * 8);

#pragma unroll
    for (int ks = 0; ks < KS; ++ks) {
        if (ks + PF - 1 < KS) {
#pragma unroll
            for (int cf = 0; cf < CF; ++cf)
                bw[(ks + PF - 1) & (PF - 1)][cf] =
                    *(const bf16x8*)(W0 + (size_t)(cb + cf * 16 + l15) * KP +
                                     (ks + PF - 1) * 32 + quad * 8);
        }
#pragma unroll
        for (int rf = 0; rf < RF; ++rf) {
            bf16x8 a = *(const bf16x8*)(act + (rf * 16 + l15) * RSx + ks * 32 + quad * 8);
#pragma unroll
            for (int cf = 0; cf < CF; ++cf)
                acc[rf][cf] = __builtin_amdgcn_mfma_f32_16x16x32_bf16(a, bw[ks & (PF - 1)][cf], acc[rf][cf], 0, 0, 0);
        }
    }
    __syncthreads();   // all waves' reads complete before in-place writes
#pragma unroll
    for (int cf = 0; cf < CF; ++cf) {
        float bs = bias[cb + cf * 16 + l15];
#pragma unroll
        for (int rf = 0; rf < RF; ++rf)
#pragma unroll
            for (int r = 0; r < 4; ++r)
                act[(rf * 16 + quad * 4 + r) * RSx + cb + cf * 16 + l15] =
                    f2bf(fmaxf(acc[rf][cf][r] + bs, 0.0f));
    }
    __syncthreads();
}

// ---------------------------------------------------------------------------
// Fused stage 2+3: one block per 8 nodes, 512 threads (8 waves = 2/SIMD).
// Round-2 champion structure. ONLY change: RS2=536 / RS3=664 (not 520/648).
// Row strides 1072B=268dw and 1328B=332dw are both =12 mod 32 banks ->
// 2-way (free) LDS aliasing on A-reads, vs 8-way (~2.9x, m136) at 520/648.
// ---------------------------------------------------------------------------
static constexpr int RS2 = 536;
static constexpr int RS3 = 664;

__global__ __launch_bounds__(512, 2) void fused_stage23_kernel(
    const float* __restrict__ node, u16* __restrict__ h, const int* __restrict__ knn,
    const u16* __restrict__ Wbf,
    const float* __restrict__ bb1, const float* __restrict__ bb2,
    const float* __restrict__ bb3, const float* __restrict__ ba1,
    const float* __restrict__ ba2,
    const float* __restrict__ bm1, const float* __restrict__ bm2,
    const float* __restrict__ w3, const float* __restrict__ b3,
    float* __restrict__ out) {
    __shared__ __align__(16) u16 act[80 * RS2 + 16 * RS3];   // 107,008 B
    u16* mlpT = act + 80 * RS2;
    int blk = blockIdx.x;              // 0..255
    int node0 = blk * 8;
    int b = node0 >> 9;
    int tid = threadIdx.x, wave = tid >> 6, lane = tid & 63;
    int quad = lane >> 4, l15 = lane & 15;
    (void)lane;

    for (int e = tid; e < 80 * 20; e += 512)
        *(u16x8*)(act + (e / 20) * RS2 + (e % 20) * 8) = (u16x8){0,0,0,0,0,0,0,0};
    __syncthreads();
    for (int e = tid; e < 72 * 3; e += 512) {
        int r = e / 3, c = e - r * 3;
        int nodei = node0 + r / 9;
        int j = knn[(size_t)nodei * 9 + (r % 9)];
        float v = node[((size_t)b * 3 + c) * M_ + j] - node[((size_t)b * 3 + c) * M_ + (nodei & 511)];
        act[r * RS2 + c] = f2bf(v);
    }
    for (int e = tid; e < 72 * 16; e += 512) {
        int r = e >> 4, s = e & 15;
        int nodei = node0 + r / 9;
        int j = knn[(size_t)nodei * 9 + (r % 9)];
        *(u16x8*)(act + r * RS2 + 8 + s * 8) =
            *(const u16x8*)(h + (size_t)(b * 512 + j) * 640 + s * 8);
    }
    __syncthreads();

    conv_inplace<5, 2, 5, 4, RS2>(act, Wbf + 43008, 160, bb1, wave * 32, l15, quad);
    conv_inplace<8, 2, 5, 4, RS2>(act, Wbf + 83968, 256, bb2, wave * 32, l15, quad);
    conv_inplace<8, 2, 5, 4, RS2>(act, Wbf + 149504, 256, bb3, wave * 32, l15, quad);

    // per-node maxpool over 9 neighbor rows, replicated into cols 256..511
    for (int e = tid; e < 8 * 32; e += 512) {
        int li = e >> 5, s = e & 31;
        int r0 = li * 9;
        float mx[8];
#pragma unroll
        for (int i = 0; i < 8; ++i) mx[i] = -3.0e38f;
#pragma unroll
        for (int kk = 0; kk < 9; ++kk) {
            u16x8 v = *(const u16x8*)(act + (r0 + kk) * RS2 + s * 8);
#pragma unroll
            for (int i = 0; i < 8; ++i) mx[i] = fmaxf(mx[i], bf2f(v[i]));
        }
        u16x8 o;
#pragma unroll
        for (int i = 0; i < 8; ++i) o[i] = f2bf(mx[i]);
#pragma unroll
        for (int kk = 0; kk < 9; ++kk)
            *(u16x8*)(act + (r0 + kk) * RS2 + 256 + s * 8) = o;
    }
    __syncthreads();

    conv_inplace<16, 4, 5, 4, RS2>(act, Wbf + 215040, 512, ba1, wave * 64, l15, quad);
    conv_inplace<16, 4, 5, 4, RS2>(act, Wbf + 477184, 512, ba2, wave * 64, l15, quad);

    // ---- stage3 tail: build mlp input tile [16 x 640] in mlpT ----
    for (int e = tid; e < 8 * 64; e += 512) {
        int li = e >> 6, s = e & 63;
        int r0 = li * 9;
        float mx[8];
#pragma unroll
        for (int i = 0; i < 8; ++i) mx[i] = -3.0e38f;
#pragma unroll
        for (int kk = 0; kk < 9; ++kk) {
            u16x8 v = *(const u16x8*)(act + (r0 + kk) * RS2 + s * 8);
#pragma unroll
            for (int i = 0; i < 8; ++i) mx[i] = fmaxf(mx[i], bf2f(v[i]));
        }
        u16x8 o;
#pragma unroll
        for (int i = 0; i < 8; ++i) o[i] = f2bf(mx[i]);
        *(u16x8*)(mlpT + li * RS3 + 128 + s * 8) = o;
    }
    // feat1 = h[node][0:128] (written by stage1)
    for (int e = tid; e < 8 * 16; e += 512) {
        int li = e >> 4, s = e & 15;
        *(u16x8*)(mlpT + li * RS3 + s * 8) =
            *(const u16x8*)(h + (size_t)(node0 + li) * 640 + s * 8);
    }
    // zero pad rows 8..15
    for (int e = tid; e < 8 * 80; e += 512) {
        int r = e / 80, seg = e - r * 80;
        *(u16x8*)(mlpT + (8 + r) * RS3 + seg * 8) = (u16x8){0,0,0,0,0,0,0,0};
    }
    __syncthreads();

    conv_inplace<20, 4, 1, 4, RS3>(mlpT, Wbf + 739328, 640, bm1, wave * 64, l15, quad);
    conv_inplace<16, 2, 1, 4, RS3>(mlpT, Wbf + 1067008, 512, bm2, wave * 32, l15, quad);

    if (tid < 32) {
        int li = tid >> 2, oc = tid & 3;
        const u16* row = mlpT + li * RS3;
        const float* wrow = w3 + oc * 256;
        float a = 0.0f;
        for (int c = 0; c < 256; c += 4) {
            a += bf2f(row[c]) * wrow[c];
            a += bf2f(row[c + 1]) * wrow[c + 1];
            a += bf2f(row[c + 2]) * wrow[c + 2];
            a += bf2f(row[c + 3]) * wrow[c + 3];
        }
        a += b3[oc];
        int nodei = node0 + li;
        int bo = nodei >> 9, m = nodei & 511;
        if (oc < 3) {
            float nv = node[((size_t)bo * 3 + oc) * M_ + m];
            out[((size_t)bo * 3 + oc) * M_ + m] = nv;
            out[6144 + ((size_t)bo * 3 + oc) * M_ + m] = nv + a;
        } else {
            out[12288 + nodei] = fmaxf(a, 0.0f) + log1pf(expf(-fabsf(a))) + 0.001f;
        }
    }
}

// ---------------------------------------------------------------------------
extern "C" void kernel_launch(void* const* d_in, const int* in_sizes, int n_in,
                              void* d_out, int out_size, void* d_ws, size_t ws_size,
                              hipStream_t stream) {
    (void)in_sizes; (void)n_in; (void)out_size; (void)ws_size;
    const float* x = (const float*)d_in[0];
    const float* sn = (const float*)d_in[1];
    const float* node = (const float*)d_in[2];
    const float* W[13];
    const float* Bs[13];
    for (int i = 0; i < 13; ++i) {
        W[i] = (const float*)d_in[3 + 2 * i];
        Bs[i] = (const float*)d_in[4 + 2 * i];
    }
    float* out = (float*)d_out;

    char* ws = (char*)d_ws;
    int* idx = (int*)(ws + 0);                 //   524,288
    int* knn = (int*)(ws + 524288);            //    73,728
    u16* Wbf = (u16*)(ws + 598016);            // 2,396,160
    u16* h   = (u16*)(ws + 2994176);           // 2,621,440 (2048 x 640)

    WConvArgs wa;
    for (int w = 0; w < 12; ++w) wa.src[w] = W[w];

    prep_kernel<<<7240, 256, 0, stream>>>(x, node, idx, knn, wa, Wbf);

    fused_stage1_kernel<<<512, 256, 0, stream>>>(x, sn, node, idx, Wbf,
                                                 Bs[0], Bs[1], Bs[2], Bs[3], Bs[4], h);
    fused_stage23_kernel<<<256, 512, 0, stream>>>(node, h, knn, Wbf,
                                                  Bs[5], Bs[6], Bs[7], Bs[8], Bs[9],
                                                  Bs[10], Bs[11], W[12], Bs[12], out);
}